// Round 17
// baseline (3442.106 us; speedup 1.0000x reference)
//
#include <hip/hip_runtime.h>
#include <math.h>

#define ND    8388608
#define NTOK  8192
#define DIM   1024
#define NEXP  8
#define CAP   1024
#define TSEQ  2048

typedef short bf16x8 __attribute__((ext_vector_type(8)));
typedef unsigned short u16x8 __attribute__((ext_vector_type(8)));
typedef float f32x4 __attribute__((ext_vector_type(4)));

#define AS1 __attribute__((address_space(1)))
#define AS3 __attribute__((address_space(3)))

__device__ __forceinline__ void gload_lds16(const void* g, void* l) {
    __builtin_amdgcn_global_load_lds((const AS1 unsigned int*)g,
                                     (AS3 unsigned int*)l, 16, 0, 0);
}

__device__ __forceinline__ unsigned short f2bf(float x) {
    union { float f; unsigned u; } v; v.f = x;
    unsigned r = v.u + 0x7FFFu + ((v.u >> 16) & 1u);
    return (unsigned short)(r >> 16);
}
__device__ __forceinline__ float bf2f(unsigned short b) {
    union { unsigned u; float f; } v; v.u = ((unsigned)b) << 16; return v.f;
}

// ---------------- init: rc/rs/ctl ----------------
__global__ void k_init_small(const float* __restrict__ phase, const int* __restrict__ Lptr,
                             float* __restrict__ rc, float* __restrict__ rs,
                             int* __restrict__ ctl) {
    int d = blockIdx.x * blockDim.x + threadIdx.x;
    if (d < DIM) { rc[d] = cosf(phase[d]); rs[d] = sinf(phase[d]); }
    if (d == 0) {
        ctl[0] = 0; ctl[1] = 0;
        int L = Lptr[0]; int mi = L - 1; if (mi < 1) mi = 1;
        ctl[2] = mi;
    }
}

// ---------------- one-time: We -> weT hi/lo bf16, [e][h][d], slot-swizzled by h&7 ----------------
__global__ __launch_bounds__(256) void k_wconv(const float* __restrict__ We,
                                               unsigned short* __restrict__ Whi,
                                               unsigned short* __restrict__ Wlo) {
    __shared__ float lds[64][65];
    int e = blockIdx.z, h0 = blockIdx.x * 64, d0 = blockIdx.y * 64;
    int tid = threadIdx.x;
    #pragma unroll
    for (int q = 0; q < 16; ++q) {
        int idx = q * 256 + tid;
        int i = idx >> 6, j = idx & 63;
        lds[i][j] = We[(size_t)e * 1048576 + (size_t)(d0 + i) * 1024 + h0 + j];
    }
    __syncthreads();
    #pragma unroll
    for (int q = 0; q < 2; ++q) {
        int sid = q * 256 + tid;
        int j = sid >> 3, sp = sid & 7;
        int h = h0 + j;
        int slog = sp ^ (h & 7);
        u16x8 hi, lo;
        #pragma unroll
        for (int u = 0; u < 8; ++u) {
            float x = lds[slog * 8 + u][j];
            unsigned short hb = f2bf(x);
            hi[u] = hb;
            lo[u] = f2bf(x - bf2f(hb));
        }
        size_t o = (((size_t)(e << 10) + h) << 10) + d0 + sp * 8;
        *(u16x8*)(Whi + o) = hi;
        *(u16x8*)(Wlo + o) = lo;
    }
}

// ---------------- fused init + gate ----------------
__global__ __launch_bounds__(256) void k_init_gate(
    const float* __restrict__ xr, const float* __restrict__ xi,
    unsigned short* __restrict__ zhi, unsigned short* __restrict__ zlo,
    unsigned short* __restrict__ zimB,
    const float* __restrict__ Wg, const float* __restrict__ bg,
    float* __restrict__ S, int* __restrict__ tokcnt) {
    const int w = threadIdx.x >> 6, lane = threadIdx.x & 63;
    const int n = blockIdx.x * 4 + w;
    float acc[8] = {0,0,0,0,0,0,0,0};
    #pragma unroll
    for (int q = 0; q < 4; ++q) {
        const int d0 = q * 256 + lane * 4;
        const size_t base = ((size_t)n << 10) + d0;
        float4 xv = *(const float4*)(xr + base);
        float4 iv = *(const float4*)(xi + base);
        float zz[4] = {xv.x, xv.y, xv.z, xv.w};
        float zi[4] = {iv.x, iv.y, iv.z, iv.w};
        unsigned short h4[4], l4[4], i4[4];
        #pragma unroll
        for (int j = 0; j < 4; ++j) {
            unsigned short hb = f2bf(zz[j]);
            h4[j] = hb;
            l4[j] = f2bf(zz[j] - bf2f(hb));
            i4[j] = f2bf(zi[j]);
            const float4 w0 = *(const float4*)(Wg + (d0 + j) * 8);
            const float4 w1 = *(const float4*)(Wg + (d0 + j) * 8 + 4);
            acc[0] += zz[j] * w0.x; acc[1] += zz[j] * w0.y; acc[2] += zz[j] * w0.z; acc[3] += zz[j] * w0.w;
            acc[4] += zz[j] * w1.x; acc[5] += zz[j] * w1.y; acc[6] += zz[j] * w1.z; acc[7] += zz[j] * w1.w;
        }
        *(ushort4*)(zhi + base)  = (ushort4){h4[0], h4[1], h4[2], h4[3]};
        *(ushort4*)(zlo + base)  = (ushort4){l4[0], l4[1], l4[2], l4[3]};
        *(ushort4*)(zimB + base) = (ushort4){i4[0], i4[1], i4[2], i4[3]};
    }
    #pragma unroll
    for (int off = 32; off > 0; off >>= 1)
        #pragma unroll
        for (int e = 0; e < 8; ++e) acc[e] += __shfl_xor(acc[e], off);
    if (lane == 0) {
        float m = -1e30f;
        #pragma unroll
        for (int e = 0; e < 8; ++e) { acc[e] += bg[e]; m = fmaxf(m, acc[e]); }
        float sum = 0.f;
        #pragma unroll
        for (int e = 0; e < 8; ++e) { acc[e] = expf(acc[e] - m); sum += acc[e]; }
        float inv = 1.0f / sum;
        *(float4*)(S + (n << 3))     = (float4){acc[0]*inv, acc[1]*inv, acc[2]*inv, acc[3]*inv};
        *(float4*)(S + (n << 3) + 4) = (float4){acc[4]*inv, acc[5]*inv, acc[6]*inv, acc[7]*inv};
        tokcnt[n] = 0;
    }
}

// ---------------- radix select + emit (fused) ----------------
__global__ __launch_bounds__(1024) void k_route(
    const float* __restrict__ S, int* __restrict__ idxs, int* __restrict__ tokcnt,
    int* __restrict__ ent_id, const int* __restrict__ ctl, int iter) {
    if (iter >= 0 && (ctl[0] || iter >= ctl[2])) return;
    __shared__ unsigned keys[NTOK];
    __shared__ unsigned hA[2048];
    __shared__ unsigned hB[2048];
    __shared__ int sbkt, srem, sntie, scnt;
    const int e = blockIdx.x, tid = threadIdx.x;
    if (tid == 0) scnt = 0;
    for (int n = tid; n < NTOK; n += 1024) keys[n] = __float_as_uint(S[(n << 3) + e]);
    __syncthreads();

    int rem = CAP;
    unsigned pref = 0;
    #pragma unroll
    for (int lvl = 0; lvl < 3; ++lvl) {
        const int nb = (lvl == 2) ? 1024 : 2048;
        for (int i = tid; i < nb; i += 1024) hA[i] = 0;
        __syncthreads();
        for (int n = tid; n < NTOK; n += 1024) {
            unsigned k = keys[n];
            bool ok; unsigned b;
            if (lvl == 0)      { ok = true;                 b = k >> 21; }
            else if (lvl == 1) { ok = (k >> 21) == pref;    b = (k >> 10) & 2047u; }
            else               { ok = (k >> 10) == pref;    b = k & 1023u; }
            if (ok) atomicAdd(&hA[b], 1u);
        }
        __syncthreads();
        unsigned* src = hA; unsigned* dst = hB;
        for (int off = 1; off < nb; off <<= 1) {
            for (int i = tid; i < nb; i += 1024)
                dst[i] = src[i] + ((i + off < nb) ? src[i + off] : 0u);
            __syncthreads();
            unsigned* t = src; src = dst; dst = t;
        }
        for (int i = tid; i < nb; i += 1024) {
            unsigned sfi = src[i];
            unsigned sfn = (i + 1 < nb) ? src[i + 1] : 0u;
            if (sfi >= (unsigned)rem && sfn < (unsigned)rem) {
                sbkt = i; srem = rem - (int)sfn; sntie = (int)(sfi - sfn);
            }
        }
        __syncthreads();
        int b = sbkt; rem = srem;
        if (lvl == 0)      pref = (unsigned)b;
        else if (lvl == 1) pref = (pref << 11) | (unsigned)b;
        else               pref = (pref << 10) | (unsigned)b;
        __syncthreads();
    }
    const unsigned T = pref;
    const int remv = rem;
    const bool allt = (remv == sntie);

    for (int n = tid; n < NTOK; n += 1024) {
        unsigned k = keys[n];
        bool sel = (k > T);
        if (k == T) {
            if (allt) sel = true;
            else {
                int r = 0;
                int j = 0;
                for (; j + 8 <= n; j += 8) {
                    r += (int)(keys[j] == T) + (int)(keys[j+1] == T) + (int)(keys[j+2] == T)
                       + (int)(keys[j+3] == T) + (int)(keys[j+4] == T) + (int)(keys[j+5] == T)
                       + (int)(keys[j+6] == T) + (int)(keys[j+7] == T);
                }
                for (; j < n; ++j) r += (int)(keys[j] == T);
                sel = (r < remv);
            }
        }
        if (sel) {
            int slot = atomicAdd(&scnt, 1);
            int row = (e << 10) + slot;
            idxs[row] = n;
            int p = atomicAdd(&tokcnt[n], 1);
            ent_id[(n << 3) + p] = row;
        }
    }
}

// ---------------- fused complex GEMM: LDS tiles Ahi/Alo/Whi (48KB); Aim/Wlo direct per-lane ----------------
// re = Ahi*Whi + Ahi*Wlo + Alo*Whi (+be), im = Aim*Whi  -- 3 blocks/CU
__global__ __launch_bounds__(256, 3) void k_gemm_cx(
    const unsigned short* __restrict__ zhi, const unsigned short* __restrict__ zlo,
    const unsigned short* __restrict__ zimB,
    const unsigned short* __restrict__ Whi, const unsigned short* __restrict__ Wlo,
    const float* __restrict__ be, const int* __restrict__ idxs,
    float* __restrict__ outre, unsigned short* __restrict__ outim,
    const int* __restrict__ ctl, int iter) {
    if (iter >= 0 && (ctl[0] || iter >= ctl[2])) return;
    extern __shared__ unsigned short smem[];   // 24576 shorts = 48KB: Ahi@0, Alo@8192, Whi@16384
    const int bid = blockIdx.x;
    const int e = bid & 7, bx = (bid >> 3) & 7, by = bid >> 6;
    const int tid = threadIdx.x;
    const int wid = tid >> 6, lane = tid & 63;
    const int wm = wid >> 1, wn = wid & 1;
    const int rl = lane >> 3, ch = lane & 7;
    const int swz8 = (ch ^ rl) << 3;

    // staging: 48 chunks (3 tiles x 16), 12 per wave; per-lane source rows hoisted
    const unsigned short* sp[12];
    int dofs[12];
    #pragma unroll
    for (int i = 0; i < 12; ++i) {
        int idx = wid * 12 + i;
        int T = idx >> 4, c = idx & 15;
        int row;
        const unsigned short* plane;
        int col;
        if (T == 0)      { plane = zhi; row = idxs[(e << 10) + by * 128 + c * 8 + rl]; col = swz8; }
        else if (T == 1) { plane = zlo; row = idxs[(e << 10) + by * 128 + c * 8 + rl]; col = swz8; }
        else             { plane = Whi; row = (e << 10) + bx * 128 + c * 8 + rl;       col = ch << 3; }
        sp[i] = plane + ((size_t)row << 10) + col;
        dofs[i] = (T << 13) + c * 512;
    }

    // direct-load row indices for Aim (gathered) and Wlo (dense)
    int tokam[4], wrow[4];
    #pragma unroll
    for (int mi = 0; mi < 4; ++mi)
        tokam[mi] = idxs[(e << 10) + by * 128 + wm * 64 + mi * 16 + (lane & 15)];
    #pragma unroll
    for (int ni = 0; ni < 4; ++ni)
        wrow[ni] = (e << 10) + bx * 128 + wn * 64 + ni * 16 + (lane & 15);

    f32x4 accre[4][4], accim[4][4];
    #pragma unroll
    for (int a = 0; a < 4; ++a)
        #pragma unroll
        for (int b = 0; b < 4; ++b) {
            accre[a][b] = (f32x4){0.f, 0.f, 0.f, 0.f};
            accim[a][b] = (f32x4){0.f, 0.f, 0.f, 0.f};
        }

    for (int kt = 0; kt < DIM; kt += 64) {
        if (kt) __syncthreads();
        #pragma unroll
        for (int i = 0; i < 12; ++i)
            gload_lds16(sp[i] + kt, smem + dofs[i]);
        __syncthreads();
        #pragma unroll
        for (int ks = 0; ks < 2; ++ks) {
            const int slog = (ks << 2) + (lane >> 4);
            const int swz = (slog ^ (lane & 7)) << 3;
            bf16x8 ah[4], al[4], am[4], bh[4], bl[4];
            #pragma unroll
            for (int mi = 0; mi < 4; ++mi) {
                int off = ((wm * 64 + mi * 16 + (lane & 15)) << 6) + swz;
                ah[mi] = *(const bf16x8*)&smem[off];
                al[mi] = *(const bf16x8*)&smem[8192 + off];
                am[mi] = *(const bf16x8*)(zimB + (((size_t)tokam[mi]) << 10) + kt + (slog << 3));
            }
            #pragma unroll
            for (int ni = 0; ni < 4; ++ni) {
                int off = ((wn * 64 + ni * 16 + (lane & 15)) << 6) + swz;
                bh[ni] = *(const bf16x8*)&smem[16384 + off];
                bl[ni] = *(const bf16x8*)(Wlo + (((size_t)wrow[ni]) << 10) + kt + swz);
            }
            #pragma unroll
            for (int mi = 0; mi < 4; ++mi)
                #pragma unroll
                for (int ni = 0; ni < 4; ++ni) {
                    accre[mi][ni] = __builtin_amdgcn_mfma_f32_16x16x32_bf16(ah[mi], bh[ni], accre[mi][ni], 0, 0, 0);
                    accre[mi][ni] = __builtin_amdgcn_mfma_f32_16x16x32_bf16(ah[mi], bl[ni], accre[mi][ni], 0, 0, 0);
                    accre[mi][ni] = __builtin_amdgcn_mfma_f32_16x16x32_bf16(al[mi], bh[ni], accre[mi][ni], 0, 0, 0);
                    accim[mi][ni] = __builtin_amdgcn_mfma_f32_16x16x32_bf16(am[mi], bh[ni], accim[mi][ni], 0, 0, 0);
                }
        }
    }
    const int colbase = bx * 128 + wn * 64 + (lane & 15);
    float bev[4];
    #pragma unroll
    for (int ni = 0; ni < 4; ++ni) bev[ni] = be[(e << 10) + colbase + ni * 16];
    const int rowloc = by * 128 + wm * 64 + ((lane >> 4) << 2);
    float* obr = outre + (((size_t)(e << 10) + rowloc) << 10) + colbase;
    unsigned short* obi = outim + (((size_t)(e << 10) + rowloc) << 10) + colbase;
    #pragma unroll
    for (int mi = 0; mi < 4; ++mi)
        #pragma unroll
        for (int rg = 0; rg < 4; ++rg) {
            size_t ro = (size_t)(mi * 16 + rg) << 10;
            #pragma unroll
            for (int ni = 0; ni < 4; ++ni) {
                obr[ro + ni * 16] = accre[mi][ni][rg] + bev[ni];
                obi[ro + ni * 16] = f2bf(accim[mi][ni][rg]);
            }
        }
}

// ---------------- fused residual + gate (fp32 pred.re, bf16 pred.im) ----------------
__global__ __launch_bounds__(256) void k_resid_gate(
    unsigned short* __restrict__ zhi, unsigned short* __restrict__ zlo,
    unsigned short* __restrict__ zimB,
    const float* __restrict__ xr, const float* __restrict__ xi,
    const float* __restrict__ rc, const float* __restrict__ rs,
    const float* __restrict__ outre, const unsigned short* __restrict__ outim,
    int* __restrict__ tokcnt, const int* __restrict__ ent_id,
    float* __restrict__ S, const float* __restrict__ Wg, const float* __restrict__ bg,
    float lr, float* __restrict__ partial, const int* __restrict__ ctl, int iter) {
    if (ctl[0] || iter >= ctl[2]) return;
    __shared__ float wred[4][8];
    const int n = blockIdx.x;
    const int tid = threadIdx.x;
    const int d0 = tid << 2;
    const int kc = tokcnt[n];
    const int4 e0 = *(const int4*)(ent_id + (n << 3));
    const int4 e1 = *(const int4*)(ent_id + (n << 3) + 4);
    const int rows[8] = {e0.x, e0.y, e0.z, e0.w, e1.x, e1.y, e1.z, e1.w};

    float pr[4] = {0,0,0,0}, pm[4] = {0,0,0,0};
    #pragma unroll
    for (int k = 0; k < 8; ++k) {
        if (k < kc) {
            const int row = rows[k];
            const float s = S[(n << 3) + (row >> 10)];
            const float4 vr = *(const float4*)(outre + ((size_t)row << 10) + d0);
            const ushort4 vi = *(const ushort4*)(outim + ((size_t)row << 10) + d0);
            pr[0] += s * vr.x; pr[1] += s * vr.y; pr[2] += s * vr.z; pr[3] += s * vr.w;
            pm[0] += s * bf2f(vi.x); pm[1] += s * bf2f(vi.y); pm[2] += s * bf2f(vi.z); pm[3] += s * bf2f(vi.w);
        }
    }
    const size_t base = ((size_t)n << 10) + d0;
    const int t = n & (TSEQ - 1);
    float tr[4], ti[4];
    if (t == 0) {
        float4 a = *(const float4*)(xr + base), b = *(const float4*)(xi + base);
        tr[0]=a.x; tr[1]=a.y; tr[2]=a.z; tr[3]=a.w;
        ti[0]=b.x; ti[1]=b.y; ti[2]=b.z; ti[3]=b.w;
    } else {
        float4 a = *(const float4*)(xr + base - DIM), b = *(const float4*)(xi + base - DIM);
        float4 c = *(const float4*)(rc + d0), s4 = *(const float4*)(rs + d0);
        tr[0]=a.x*c.x-b.x*s4.x; tr[1]=a.y*c.y-b.y*s4.y; tr[2]=a.z*c.z-b.z*s4.z; tr[3]=a.w*c.w-b.w*s4.w;
        ti[0]=a.x*s4.x+b.x*c.x; ti[1]=a.y*s4.y+b.y*c.y; ti[2]=a.z*s4.z+b.z*c.z; ti[3]=a.w*s4.w+b.w*c.w;
    }
    ushort4 h4 = *(const ushort4*)(zhi + base);
    ushort4 l4 = *(const ushort4*)(zlo + base);
    ushort4 zi4 = *(const ushort4*)(zimB + base);
    float zrv[4] = {bf2f(h4.x)+bf2f(l4.x), bf2f(h4.y)+bf2f(l4.y),
                    bf2f(h4.z)+bf2f(l4.z), bf2f(h4.w)+bf2f(l4.w)};
    unsigned short ziv[4] = {zi4.x, zi4.y, zi4.z, zi4.w};
    unsigned short hn[4], ln[4], zo[4];
    float lsum = 0.f;
    float lac[8] = {0,0,0,0,0,0,0,0};
    #pragma unroll
    for (int j = 0; j < 4; ++j) {
        float rr = tr[j] - pr[j];
        float ri = ti[j] - pm[j];
        float zn = zrv[j] + lr * rr;
        unsigned short hb = f2bf(zn);
        hn[j] = hb;
        ln[j] = f2bf(zn - bf2f(hb));
        zo[j] = f2bf(bf2f(ziv[j]) + lr * ri);
        lsum += sqrtf(rr * rr + ri * ri);
        const float4 w0 = *(const float4*)(Wg + (d0 + j) * 8);
        const float4 w1 = *(const float4*)(Wg + (d0 + j) * 8 + 4);
        lac[0] += zn * w0.x; lac[1] += zn * w0.y; lac[2] += zn * w0.z; lac[3] += zn * w0.w;
        lac[4] += zn * w1.x; lac[5] += zn * w1.y; lac[6] += zn * w1.z; lac[7] += zn * w1.w;
    }
    *(ushort4*)(zhi + base)  = (ushort4){hn[0], hn[1], hn[2], hn[3]};
    *(ushort4*)(zlo + base)  = (ushort4){ln[0], ln[1], ln[2], ln[3]};
    *(ushort4*)(zimB + base) = (ushort4){zo[0], zo[1], zo[2], zo[3]};

    const int w = tid >> 6, lane = tid & 63;
    #pragma unroll
    for (int off = 32; off > 0; off >>= 1) {
        lsum += __shfl_xor(lsum, off);
        #pragma unroll
        for (int e = 0; e < 8; ++e) lac[e] += __shfl_xor(lac[e], off);
    }
    if (lane == 0) {
        #pragma unroll
        for (int e = 0; e < 8; ++e) wred[w][e] = lac[e];
        partial[(n << 2) + w] = lsum;
    }
    __syncthreads();
    if (tid == 0) {
        float lg[8];
        float m = -1e30f;
        #pragma unroll
        for (int e = 0; e < 8; ++e) {
            lg[e] = wred[0][e] + wred[1][e] + wred[2][e] + wred[3][e] + bg[e];
            m = fmaxf(m, lg[e]);
        }
        float sum = 0.f;
        #pragma unroll
        for (int e = 0; e < 8; ++e) { lg[e] = expf(lg[e] - m); sum += lg[e]; }
        float inv = 1.0f / sum;
        *(float4*)(S + (n << 3))     = (float4){lg[0]*inv, lg[1]*inv, lg[2]*inv, lg[3]*inv};
        *(float4*)(S + (n << 3) + 4) = (float4){lg[4]*inv, lg[5]*inv, lg[6]*inv, lg[7]*inv};
        tokcnt[n] = 0;
    }
}

// ---------------- finalize ----------------
__global__ __launch_bounds__(1024) void k_finalize(
    const float* __restrict__ partial, int* __restrict__ ctl, int iter) {
    if (ctl[0] || iter >= ctl[2]) return;
    __shared__ float red[16];
    float s = 0.f;
    for (int i = threadIdx.x; i < NTOK * 4; i += 1024) s += partial[i];
    #pragma unroll
    for (int off = 32; off > 0; off >>= 1) s += __shfl_xor(s, off);
    if ((threadIdx.x & 63) == 0) red[threadIdx.x >> 6] = s;
    __syncthreads();
    if (threadIdx.x == 0) {
        float tot = 0.f;
        #pragma unroll
        for (int w = 0; w < 16; ++w) tot += red[w];
        ctl[1] = iter + 1;
        if (tot * (1.0f / (float)ND) < 0.001f) ctl[0] = 1;
    }
}

// ---------------- final z update ----------------
__global__ __launch_bounds__(256) void k_final_zupd(
    unsigned short* __restrict__ zhi, unsigned short* __restrict__ zlo,
    unsigned short* __restrict__ zimB,
    const float* __restrict__ xr, const float* __restrict__ xi,
    const float* __restrict__ rc, const float* __restrict__ rs,
    const float* __restrict__ outre, const unsigned short* __restrict__ outim,
    const int* __restrict__ tokcnt, const int* __restrict__ ent_id,
    const float* __restrict__ S) {
    const int n = blockIdx.x;
    const int tid = threadIdx.x;
    const int d0 = tid << 2;
    const int kc = tokcnt[n];
    const int4 e0 = *(const int4*)(ent_id + (n << 3));
    const int4 e1 = *(const int4*)(ent_id + (n << 3) + 4);
    const int rows[8] = {e0.x, e0.y, e0.z, e0.w, e1.x, e1.y, e1.z, e1.w};
    float pr[4] = {0,0,0,0}, pm[4] = {0,0,0,0};
    #pragma unroll
    for (int k = 0; k < 8; ++k) {
        if (k < kc) {
            const int row = rows[k];
            const float s = S[(n << 3) + (row >> 10)];
            const float4 vr = *(const float4*)(outre + ((size_t)row << 10) + d0);
            const ushort4 vi = *(const ushort4*)(outim + ((size_t)row << 10) + d0);
            pr[0] += s * vr.x; pr[1] += s * vr.y; pr[2] += s * vr.z; pr[3] += s * vr.w;
            pm[0] += s * bf2f(vi.x); pm[1] += s * bf2f(vi.y); pm[2] += s * bf2f(vi.z); pm[3] += s * bf2f(vi.w);
        }
    }
    const size_t base = ((size_t)n << 10) + d0;
    const int t = n & (TSEQ - 1);
    float tr[4], ti[4];
    if (t == 0) {
        float4 a = *(const float4*)(xr + base), b = *(const float4*)(xi + base);
        tr[0]=a.x; tr[1]=a.y; tr[2]=a.z; tr[3]=a.w;
        ti[0]=b.x; ti[1]=b.y; ti[2]=b.z; ti[3]=b.w;
    } else {
        float4 a = *(const float4*)(xr + base - DIM), b = *(const float4*)(xi + base - DIM);
        float4 c = *(const float4*)(rc + d0), s4 = *(const float4*)(rs + d0);
        tr[0]=a.x*c.x-b.x*s4.x; tr[1]=a.y*c.y-b.y*s4.y; tr[2]=a.z*c.z-b.z*s4.z; tr[3]=a.w*c.w-b.w*s4.w;
        ti[0]=a.x*s4.x+b.x*c.x; ti[1]=a.y*s4.y+b.y*c.y; ti[2]=a.z*s4.z+b.z*c.z; ti[3]=a.w*s4.w+b.w*c.w;
    }
    ushort4 h4 = *(const ushort4*)(zhi + base);
    ushort4 l4 = *(const ushort4*)(zlo + base);
    ushort4 zi4 = *(const ushort4*)(zimB + base);
    float zrv[4] = {bf2f(h4.x)+bf2f(l4.x), bf2f(h4.y)+bf2f(l4.y),
                    bf2f(h4.z)+bf2f(l4.z), bf2f(h4.w)+bf2f(l4.w)};
    unsigned short ziv[4] = {zi4.x, zi4.y, zi4.z, zi4.w};
    unsigned short hn[4], ln[4], zo[4];
    #pragma unroll
    for (int j = 0; j < 4; ++j) {
        float zn = zrv[j] + 0.5f * (tr[j] - pr[j]);
        unsigned short hb = f2bf(zn);
        hn[j] = hb;
        ln[j] = f2bf(zn - bf2f(hb));
        zo[j] = f2bf(bf2f(ziv[j]) + 0.5f * (ti[j] - pm[j]));
    }
    *(ushort4*)(zhi + base)  = (ushort4){hn[0], hn[1], hn[2], hn[3]};
    *(ushort4*)(zlo + base)  = (ushort4){ln[0], ln[1], ln[2], ln[3]};
    *(ushort4*)(zimB + base) = (ushort4){zo[0], zo[1], zo[2], zo[3]};
}

__global__ void k_write_out(const unsigned short* __restrict__ zhi,
                            const unsigned short* __restrict__ zlo,
                            const unsigned short* __restrict__ zimB,
                            float* __restrict__ out, const int* __restrict__ ctl) {
    int i = blockIdx.x * blockDim.x + threadIdx.x;
    if (i >= ND) return;
    out[2 * i]     = bf2f(zhi[i]) + bf2f(zlo[i]);
    out[2 * i + 1] = bf2f(zimB[i]);
    if (i == 0) out[(size_t)2 * ND] = (float)ctl[1];
}

// ---------------- host ----------------
extern "C" void kernel_launch(void* const* d_in, const int* in_sizes, int n_in,
                              void* d_out, int out_size, void* d_ws, size_t ws_size,
                              hipStream_t stream) {
    (void)in_sizes; (void)n_in; (void)out_size; (void)ws_size;
    const float* x_real = (const float*)d_in[0];
    const float* x_imag = (const float*)d_in[1];
    const float* phase  = (const float*)d_in[2];
    const float* Wg     = (const float*)d_in[3];
    const float* bg     = (const float*)d_in[4];
    const float* We     = (const float*)d_in[5];
    const float* be     = (const float*)d_in[6];
    const int*   Lptr   = (const int*)d_in[7];

    char* wsb = (char*)d_ws;
    unsigned short* zhi  = (unsigned short*)wsb;                      // 16MB
    unsigned short* zlo  = (unsigned short*)(wsb + 16777216);         // 16MB
    unsigned short* zimB = (unsigned short*)(wsb + 33554432);         // 16MB
    unsigned short* Whi  = (unsigned short*)(wsb + 50331648);         // 16MB
    unsigned short* Wlo  = (unsigned short*)(wsb + 67108864);         // 16MB
    float*    S       = (float*)(wsb + 83886080);       // 256KB
    int*      ent_id  = (int*)  (wsb + 84148224);       // 256KB
    int*      idxs    = (int*)  (wsb + 84410368);       // 32KB
    int*      tokcnt  = (int*)  (wsb + 84443136);       // 32KB
    float*    partial = (float*)(wsb + 84475904);       // 128KB
    float*    rc      = (float*)(wsb + 84606976);       // 4KB
    float*    rs      = (float*)(wsb + 84611072);       // 4KB
    int*      ctl     = (int*)  (wsb + 84615168);       // 12B

    float*          outre = (float*)d_out;                       // 32MB fp32 pred.re
    unsigned short* outim = (unsigned short*)((char*)d_out + 33554432);  // 16MB bf16 pred.im

    k_init_small<<<4, 256, 0, stream>>>(phase, Lptr, rc, rs, ctl);
    k_wconv<<<dim3(16, 16, 8), 256, 0, stream>>>(We, Whi, Wlo);
    k_init_gate<<<NTOK / 4, 256, 0, stream>>>(x_real, x_imag, zhi, zlo, zimB, Wg, bg, S, tokcnt);

    const size_t gemm_lds = 24576 * sizeof(unsigned short);   // 48KB -> 3 blocks/CU
    float lr = 0.5f;
    for (int it = 0; it < 7; ++it) {
        k_route<<<NEXP, 1024, 0, stream>>>(S, idxs, tokcnt, ent_id, ctl, it);
        k_gemm_cx<<<512, 256, gemm_lds, stream>>>(zhi, zlo, zimB, Whi, Wlo, be, idxs,
                                                  outre, outim, ctl, it);
        k_resid_gate<<<NTOK, 256, 0, stream>>>(zhi, zlo, zimB, x_real, x_imag, rc, rs,
                                               outre, outim, tokcnt, ent_id, S, Wg, bg,
                                               lr, partial, ctl, it);
        k_finalize<<<1, 1024, 0, stream>>>(partial, ctl, it);
        lr *= 0.85f;
    }

    k_route<<<NEXP, 1024, 0, stream>>>(S, idxs, tokcnt, ent_id, ctl, -1);
    k_gemm_cx<<<512, 256, gemm_lds, stream>>>(zhi, zlo, zimB, Whi, Wlo, be, idxs,
                                              outre, outim, ctl, -1);
    k_final_zupd<<<NTOK, 256, 0, stream>>>(zhi, zlo, zimB, x_real, x_imag, rc, rs,
                                           outre, outim, tokcnt, ent_id, S);
    k_write_out<<<ND / 256, 256, 0, stream>>>(zhi, zlo, zimB, (float*)d_out, ctl);
}

// Round 18
// 1131.799 us; speedup vs baseline: 3.0413x; 3.0413x over previous
//
#include <hip/hip_runtime.h>
#include <math.h>

#define ND    8388608
#define NTOK  8192
#define DIM   1024
#define NEXP  8
#define CAP   1024
#define TSEQ  2048

typedef short bf16x8 __attribute__((ext_vector_type(8)));
typedef unsigned short u16x8 __attribute__((ext_vector_type(8)));
typedef float f32x4 __attribute__((ext_vector_type(4)));

#define AS1 __attribute__((address_space(1)))
#define AS3 __attribute__((address_space(3)))

__device__ __forceinline__ void gload_lds16(const void* g, void* l) {
    __builtin_amdgcn_global_load_lds((const AS1 unsigned int*)g,
                                     (AS3 unsigned int*)l, 16, 0, 0);
}

__device__ __forceinline__ unsigned short f2bf(float x) {
    union { float f; unsigned u; } v; v.f = x;
    unsigned r = v.u + 0x7FFFu + ((v.u >> 16) & 1u);
    return (unsigned short)(r >> 16);
}
__device__ __forceinline__ float bf2f(unsigned short b) {
    union { unsigned u; float f; } v; v.u = ((unsigned)b) << 16; return v.f;
}

// ---------------- init: rc/rs/ctl ----------------
__global__ void k_init_small(const float* __restrict__ phase, const int* __restrict__ Lptr,
                             float* __restrict__ rc, float* __restrict__ rs,
                             int* __restrict__ ctl) {
    int d = blockIdx.x * blockDim.x + threadIdx.x;
    if (d < DIM) { rc[d] = cosf(phase[d]); rs[d] = sinf(phase[d]); }
    if (d == 0) {
        ctl[0] = 0; ctl[1] = 0;
        int L = Lptr[0]; int mi = L - 1; if (mi < 1) mi = 1;
        ctl[2] = mi;
    }
}

// ---------------- one-time: We -> weT hi/lo bf16, [e][h][d], slot-swizzled by h&7 ----------------
__global__ __launch_bounds__(256) void k_wconv(const float* __restrict__ We,
                                               unsigned short* __restrict__ Whi,
                                               unsigned short* __restrict__ Wlo) {
    __shared__ float lds[64][65];
    int e = blockIdx.z, h0 = blockIdx.x * 64, d0 = blockIdx.y * 64;
    int tid = threadIdx.x;
    #pragma unroll
    for (int q = 0; q < 16; ++q) {
        int idx = q * 256 + tid;
        int i = idx >> 6, j = idx & 63;
        lds[i][j] = We[(size_t)e * 1048576 + (size_t)(d0 + i) * 1024 + h0 + j];
    }
    __syncthreads();
    #pragma unroll
    for (int q = 0; q < 2; ++q) {
        int sid = q * 256 + tid;
        int j = sid >> 3, sp = sid & 7;
        int h = h0 + j;
        int slog = sp ^ (h & 7);
        u16x8 hi, lo;
        #pragma unroll
        for (int u = 0; u < 8; ++u) {
            float x = lds[slog * 8 + u][j];
            unsigned short hb = f2bf(x);
            hi[u] = hb;
            lo[u] = f2bf(x - bf2f(hb));
        }
        size_t o = (((size_t)(e << 10) + h) << 10) + d0 + sp * 8;
        *(u16x8*)(Whi + o) = hi;
        *(u16x8*)(Wlo + o) = lo;
    }
}

// ---------------- fused init + gate ----------------
__global__ __launch_bounds__(256) void k_init_gate(
    const float* __restrict__ xr, const float* __restrict__ xi,
    unsigned short* __restrict__ zhi, unsigned short* __restrict__ zlo,
    unsigned short* __restrict__ zimB,
    const float* __restrict__ Wg, const float* __restrict__ bg,
    float* __restrict__ S, int* __restrict__ tokcnt) {
    const int w = threadIdx.x >> 6, lane = threadIdx.x & 63;
    const int n = blockIdx.x * 4 + w;
    float acc[8] = {0,0,0,0,0,0,0,0};
    #pragma unroll
    for (int q = 0; q < 4; ++q) {
        const int d0 = q * 256 + lane * 4;
        const size_t base = ((size_t)n << 10) + d0;
        float4 xv = *(const float4*)(xr + base);
        float4 iv = *(const float4*)(xi + base);
        float zz[4] = {xv.x, xv.y, xv.z, xv.w};
        float zi[4] = {iv.x, iv.y, iv.z, iv.w};
        unsigned short h4[4], l4[4], i4[4];
        #pragma unroll
        for (int j = 0; j < 4; ++j) {
            unsigned short hb = f2bf(zz[j]);
            h4[j] = hb;
            l4[j] = f2bf(zz[j] - bf2f(hb));
            i4[j] = f2bf(zi[j]);
            const float4 w0 = *(const float4*)(Wg + (d0 + j) * 8);
            const float4 w1 = *(const float4*)(Wg + (d0 + j) * 8 + 4);
            acc[0] += zz[j] * w0.x; acc[1] += zz[j] * w0.y; acc[2] += zz[j] * w0.z; acc[3] += zz[j] * w0.w;
            acc[4] += zz[j] * w1.x; acc[5] += zz[j] * w1.y; acc[6] += zz[j] * w1.z; acc[7] += zz[j] * w1.w;
        }
        *(ushort4*)(zhi + base)  = (ushort4){h4[0], h4[1], h4[2], h4[3]};
        *(ushort4*)(zlo + base)  = (ushort4){l4[0], l4[1], l4[2], l4[3]};
        *(ushort4*)(zimB + base) = (ushort4){i4[0], i4[1], i4[2], i4[3]};
    }
    #pragma unroll
    for (int off = 32; off > 0; off >>= 1)
        #pragma unroll
        for (int e = 0; e < 8; ++e) acc[e] += __shfl_xor(acc[e], off);
    if (lane == 0) {
        float m = -1e30f;
        #pragma unroll
        for (int e = 0; e < 8; ++e) { acc[e] += bg[e]; m = fmaxf(m, acc[e]); }
        float sum = 0.f;
        #pragma unroll
        for (int e = 0; e < 8; ++e) { acc[e] = expf(acc[e] - m); sum += acc[e]; }
        float inv = 1.0f / sum;
        *(float4*)(S + (n << 3))     = (float4){acc[0]*inv, acc[1]*inv, acc[2]*inv, acc[3]*inv};
        *(float4*)(S + (n << 3) + 4) = (float4){acc[4]*inv, acc[5]*inv, acc[6]*inv, acc[7]*inv};
        tokcnt[n] = 0;
    }
}

// ---------------- radix select + emit (fused) ----------------
__global__ __launch_bounds__(1024) void k_route(
    const float* __restrict__ S, int* __restrict__ idxs, int* __restrict__ tokcnt,
    int* __restrict__ ent_id, const int* __restrict__ ctl, int iter) {
    if (iter >= 0 && (ctl[0] || iter >= ctl[2])) return;
    __shared__ unsigned keys[NTOK];
    __shared__ unsigned hA[2048];
    __shared__ unsigned hB[2048];
    __shared__ int sbkt, srem, sntie, scnt;
    const int e = blockIdx.x, tid = threadIdx.x;
    if (tid == 0) scnt = 0;
    for (int n = tid; n < NTOK; n += 1024) keys[n] = __float_as_uint(S[(n << 3) + e]);
    __syncthreads();

    int rem = CAP;
    unsigned pref = 0;
    #pragma unroll
    for (int lvl = 0; lvl < 3; ++lvl) {
        const int nb = (lvl == 2) ? 1024 : 2048;
        for (int i = tid; i < nb; i += 1024) hA[i] = 0;
        __syncthreads();
        for (int n = tid; n < NTOK; n += 1024) {
            unsigned k = keys[n];
            bool ok; unsigned b;
            if (lvl == 0)      { ok = true;                 b = k >> 21; }
            else if (lvl == 1) { ok = (k >> 21) == pref;    b = (k >> 10) & 2047u; }
            else               { ok = (k >> 10) == pref;    b = k & 1023u; }
            if (ok) atomicAdd(&hA[b], 1u);
        }
        __syncthreads();
        unsigned* src = hA; unsigned* dst = hB;
        for (int off = 1; off < nb; off <<= 1) {
            for (int i = tid; i < nb; i += 1024)
                dst[i] = src[i] + ((i + off < nb) ? src[i + off] : 0u);
            __syncthreads();
            unsigned* t = src; src = dst; dst = t;
        }
        for (int i = tid; i < nb; i += 1024) {
            unsigned sfi = src[i];
            unsigned sfn = (i + 1 < nb) ? src[i + 1] : 0u;
            if (sfi >= (unsigned)rem && sfn < (unsigned)rem) {
                sbkt = i; srem = rem - (int)sfn; sntie = (int)(sfi - sfn);
            }
        }
        __syncthreads();
        int b = sbkt; rem = srem;
        if (lvl == 0)      pref = (unsigned)b;
        else if (lvl == 1) pref = (pref << 11) | (unsigned)b;
        else               pref = (pref << 10) | (unsigned)b;
        __syncthreads();
    }
    const unsigned T = pref;
    const int remv = rem;
    const bool allt = (remv == sntie);

    for (int n = tid; n < NTOK; n += 1024) {
        unsigned k = keys[n];
        bool sel = (k > T);
        if (k == T) {
            if (allt) sel = true;
            else {
                int r = 0;
                int j = 0;
                for (; j + 8 <= n; j += 8) {
                    r += (int)(keys[j] == T) + (int)(keys[j+1] == T) + (int)(keys[j+2] == T)
                       + (int)(keys[j+3] == T) + (int)(keys[j+4] == T) + (int)(keys[j+5] == T)
                       + (int)(keys[j+6] == T) + (int)(keys[j+7] == T);
                }
                for (; j < n; ++j) r += (int)(keys[j] == T);
                sel = (r < remv);
            }
        }
        if (sel) {
            int slot = atomicAdd(&scnt, 1);
            int row = (e << 10) + slot;
            idxs[row] = n;
            int p = atomicAdd(&tokcnt[n], 1);
            ent_id[(n << 3) + p] = row;
        }
    }
}

// ---------------- fused complex GEMM: fp32 pred.re, bf16 pred.im ----------------
__global__ __launch_bounds__(256, 2) void k_gemm_cx(
    const unsigned short* __restrict__ zhi, const unsigned short* __restrict__ zlo,
    const unsigned short* __restrict__ zimB,
    const unsigned short* __restrict__ Whi, const unsigned short* __restrict__ Wlo,
    const float* __restrict__ be, const int* __restrict__ idxs,
    float* __restrict__ outre, unsigned short* __restrict__ outim,
    const int* __restrict__ ctl, int iter) {
    if (iter >= 0 && (ctl[0] || iter >= ctl[2])) return;
    extern __shared__ unsigned short smem[];   // 40960 shorts = 80KB
    const int bid = blockIdx.x;
    const int e = bid & 7, bx = (bid >> 3) & 7, by = bid >> 6;
    const int tid = threadIdx.x;
    const int wid = tid >> 6, lane = tid & 63;
    const int wm = wid >> 1, wn = wid & 1;
    const int rl = lane >> 3, ch = lane & 7;
    const int swz8 = (ch ^ rl) << 3;

    int tok[16];
    if (wid < 3) {
        #pragma unroll
        for (int c = 0; c < 16; ++c)
            tok[c] = idxs[(e << 10) + by * 128 + c * 8 + rl];
    }
    const unsigned short* aplane = (wid == 0) ? zhi : (wid == 1) ? zlo : zimB;
    unsigned short* albase = smem + (wid << 13);

    const int wrowbase = (e << 10) + bx * 128;
    const unsigned short* whsrc = Whi + (((size_t)(wrowbase + rl)) << 10) + (ch << 3);
    const unsigned short* wlsrc = Wlo + (((size_t)(wrowbase + rl)) << 10) + (ch << 3);

    f32x4 accre[4][4], accim[4][4];
    #pragma unroll
    for (int a = 0; a < 4; ++a)
        #pragma unroll
        for (int b = 0; b < 4; ++b) {
            accre[a][b] = (f32x4){0.f, 0.f, 0.f, 0.f};
            accim[a][b] = (f32x4){0.f, 0.f, 0.f, 0.f};
        }

    for (int kt = 0; kt < DIM; kt += 64) {
        if (kt) __syncthreads();
        if (wid < 3) {
            #pragma unroll
            for (int c = 0; c < 16; ++c)
                gload_lds16(aplane + (((size_t)tok[c]) << 10) + kt + swz8, albase + c * 512);
        } else {
            #pragma unroll
            for (int c = 0; c < 16; ++c)
                gload_lds16(whsrc + kt + ((size_t)c << 13), smem + 24576 + c * 512);
        }
        #pragma unroll
        for (int q = 0; q < 4; ++q) {
            int c = (wid << 2) + q;
            gload_lds16(wlsrc + kt + ((size_t)c << 13), smem + 32768 + c * 512);
        }
        __syncthreads();
        #pragma unroll
        for (int ks = 0; ks < 2; ++ks) {
            const int slog = (ks << 2) + (lane >> 4);
            const int swz = (slog ^ (lane & 7)) << 3;
            bf16x8 ah[4], al[4], am[4], bh[4], bl[4];
            #pragma unroll
            for (int mi = 0; mi < 4; ++mi) {
                int off = ((wm * 64 + mi * 16 + (lane & 15)) << 6) + swz;
                ah[mi] = *(const bf16x8*)&smem[off];
                al[mi] = *(const bf16x8*)&smem[8192 + off];
                am[mi] = *(const bf16x8*)&smem[16384 + off];
            }
            #pragma unroll
            for (int ni = 0; ni < 4; ++ni) {
                int off = ((wn * 64 + ni * 16 + (lane & 15)) << 6) + swz;
                bh[ni] = *(const bf16x8*)&smem[24576 + off];
                bl[ni] = *(const bf16x8*)&smem[32768 + off];
            }
            #pragma unroll
            for (int mi = 0; mi < 4; ++mi)
                #pragma unroll
                for (int ni = 0; ni < 4; ++ni) {
                    accre[mi][ni] = __builtin_amdgcn_mfma_f32_16x16x32_bf16(ah[mi], bh[ni], accre[mi][ni], 0, 0, 0);
                    accre[mi][ni] = __builtin_amdgcn_mfma_f32_16x16x32_bf16(ah[mi], bl[ni], accre[mi][ni], 0, 0, 0);
                    accre[mi][ni] = __builtin_amdgcn_mfma_f32_16x16x32_bf16(al[mi], bh[ni], accre[mi][ni], 0, 0, 0);
                    accim[mi][ni] = __builtin_amdgcn_mfma_f32_16x16x32_bf16(am[mi], bh[ni], accim[mi][ni], 0, 0, 0);
                }
        }
    }
    const int colbase = bx * 128 + wn * 64 + (lane & 15);
    float bev[4];
    #pragma unroll
    for (int ni = 0; ni < 4; ++ni) bev[ni] = be[(e << 10) + colbase + ni * 16];
    const int rowloc = by * 128 + wm * 64 + ((lane >> 4) << 2);
    float* obr = outre + (((size_t)(e << 10) + rowloc) << 10) + colbase;
    unsigned short* obi = outim + (((size_t)(e << 10) + rowloc) << 10) + colbase;
    #pragma unroll
    for (int mi = 0; mi < 4; ++mi)
        #pragma unroll
        for (int rg = 0; rg < 4; ++rg) {
            size_t ro = (size_t)(mi * 16 + rg) << 10;
            #pragma unroll
            for (int ni = 0; ni < 4; ++ni) {
                obr[ro + ni * 16] = accre[mi][ni][rg] + bev[ni];
                obi[ro + ni * 16] = f2bf(accim[mi][ni][rg]);
            }
        }
}

// ---------------- fused residual + gate (fp32 pred.re, bf16 pred.im) ----------------
__global__ __launch_bounds__(256) void k_resid_gate(
    unsigned short* __restrict__ zhi, unsigned short* __restrict__ zlo,
    unsigned short* __restrict__ zimB,
    const float* __restrict__ xr, const float* __restrict__ xi,
    const float* __restrict__ rc, const float* __restrict__ rs,
    const float* __restrict__ outre, const unsigned short* __restrict__ outim,
    int* __restrict__ tokcnt, const int* __restrict__ ent_id,
    float* __restrict__ S, const float* __restrict__ Wg, const float* __restrict__ bg,
    float lr, float* __restrict__ partial, const int* __restrict__ ctl, int iter) {
    if (ctl[0] || iter >= ctl[2]) return;
    __shared__ float wred[4][8];
    const int n = blockIdx.x;
    const int tid = threadIdx.x;
    const int d0 = tid << 2;
    const int kc = tokcnt[n];
    const int4 e0 = *(const int4*)(ent_id + (n << 3));
    const int4 e1 = *(const int4*)(ent_id + (n << 3) + 4);
    const int rows[8] = {e0.x, e0.y, e0.z, e0.w, e1.x, e1.y, e1.z, e1.w};

    float pr[4] = {0,0,0,0}, pm[4] = {0,0,0,0};
    #pragma unroll
    for (int k = 0; k < 8; ++k) {
        if (k < kc) {
            const int row = rows[k];
            const float s = S[(n << 3) + (row >> 10)];
            const float4 vr = *(const float4*)(outre + ((size_t)row << 10) + d0);
            const ushort4 vi = *(const ushort4*)(outim + ((size_t)row << 10) + d0);
            pr[0] += s * vr.x; pr[1] += s * vr.y; pr[2] += s * vr.z; pr[3] += s * vr.w;
            pm[0] += s * bf2f(vi.x); pm[1] += s * bf2f(vi.y); pm[2] += s * bf2f(vi.z); pm[3] += s * bf2f(vi.w);
        }
    }
    const size_t base = ((size_t)n << 10) + d0;
    const int t = n & (TSEQ - 1);
    float tr[4], ti[4];
    if (t == 0) {
        float4 a = *(const float4*)(xr + base), b = *(const float4*)(xi + base);
        tr[0]=a.x; tr[1]=a.y; tr[2]=a.z; tr[3]=a.w;
        ti[0]=b.x; ti[1]=b.y; ti[2]=b.z; ti[3]=b.w;
    } else {
        float4 a = *(const float4*)(xr + base - DIM), b = *(const float4*)(xi + base - DIM);
        float4 c = *(const float4*)(rc + d0), s4 = *(const float4*)(rs + d0);
        tr[0]=a.x*c.x-b.x*s4.x; tr[1]=a.y*c.y-b.y*s4.y; tr[2]=a.z*c.z-b.z*s4.z; tr[3]=a.w*c.w-b.w*s4.w;
        ti[0]=a.x*s4.x+b.x*c.x; ti[1]=a.y*s4.y+b.y*c.y; ti[2]=a.z*s4.z+b.z*c.z; ti[3]=a.w*s4.w+b.w*c.w;
    }
    ushort4 h4 = *(const ushort4*)(zhi + base);
    ushort4 l4 = *(const ushort4*)(zlo + base);
    ushort4 zi4 = *(const ushort4*)(zimB + base);
    float zrv[4] = {bf2f(h4.x)+bf2f(l4.x), bf2f(h4.y)+bf2f(l4.y),
                    bf2f(h4.z)+bf2f(l4.z), bf2f(h4.w)+bf2f(l4.w)};
    unsigned short ziv[4] = {zi4.x, zi4.y, zi4.z, zi4.w};
    unsigned short hn[4], ln[4], zo[4];
    float lsum = 0.f;
    float lac[8] = {0,0,0,0,0,0,0,0};
    #pragma unroll
    for (int j = 0; j < 4; ++j) {
        float rr = tr[j] - pr[j];
        float ri = ti[j] - pm[j];
        float zn = zrv[j] + lr * rr;
        unsigned short hb = f2bf(zn);
        hn[j] = hb;
        ln[j] = f2bf(zn - bf2f(hb));
        zo[j] = f2bf(bf2f(ziv[j]) + lr * ri);
        lsum += sqrtf(rr * rr + ri * ri);
        const float4 w0 = *(const float4*)(Wg + (d0 + j) * 8);
        const float4 w1 = *(const float4*)(Wg + (d0 + j) * 8 + 4);
        lac[0] += zn * w0.x; lac[1] += zn * w0.y; lac[2] += zn * w0.z; lac[3] += zn * w0.w;
        lac[4] += zn * w1.x; lac[5] += zn * w1.y; lac[6] += zn * w1.z; lac[7] += zn * w1.w;
    }
    *(ushort4*)(zhi + base)  = (ushort4){hn[0], hn[1], hn[2], hn[3]};
    *(ushort4*)(zlo + base)  = (ushort4){ln[0], ln[1], ln[2], ln[3]};
    *(ushort4*)(zimB + base) = (ushort4){zo[0], zo[1], zo[2], zo[3]};

    const int w = tid >> 6, lane = tid & 63;
    #pragma unroll
    for (int off = 32; off > 0; off >>= 1) {
        lsum += __shfl_xor(lsum, off);
        #pragma unroll
        for (int e = 0; e < 8; ++e) lac[e] += __shfl_xor(lac[e], off);
    }
    if (lane == 0) {
        #pragma unroll
        for (int e = 0; e < 8; ++e) wred[w][e] = lac[e];
        partial[(n << 2) + w] = lsum;
    }
    __syncthreads();
    if (tid == 0) {
        float lg[8];
        float m = -1e30f;
        #pragma unroll
        for (int e = 0; e < 8; ++e) {
            lg[e] = wred[0][e] + wred[1][e] + wred[2][e] + wred[3][e] + bg[e];
            m = fmaxf(m, lg[e]);
        }
        float sum = 0.f;
        #pragma unroll
        for (int e = 0; e < 8; ++e) { lg[e] = expf(lg[e] - m); sum += lg[e]; }
        float inv = 1.0f / sum;
        *(float4*)(S + (n << 3))     = (float4){lg[0]*inv, lg[1]*inv, lg[2]*inv, lg[3]*inv};
        *(float4*)(S + (n << 3) + 4) = (float4){lg[4]*inv, lg[5]*inv, lg[6]*inv, lg[7]*inv};
        tokcnt[n] = 0;
    }
}

// ---------------- finalize ----------------
__global__ __launch_bounds__(1024) void k_finalize(
    const float* __restrict__ partial, int* __restrict__ ctl, int iter) {
    if (ctl[0] || iter >= ctl[2]) return;
    __shared__ float red[16];
    float s = 0.f;
    for (int i = threadIdx.x; i < NTOK * 4; i += 1024) s += partial[i];
    #pragma unroll
    for (int off = 32; off > 0; off >>= 1) s += __shfl_xor(s, off);
    if ((threadIdx.x & 63) == 0) red[threadIdx.x >> 6] = s;
    __syncthreads();
    if (threadIdx.x == 0) {
        float tot = 0.f;
        #pragma unroll
        for (int w = 0; w < 16; ++w) tot += red[w];
        ctl[1] = iter + 1;
        if (tot * (1.0f / (float)ND) < 0.001f) ctl[0] = 1;
    }
}

// ---------------- final z update ----------------
__global__ __launch_bounds__(256) void k_final_zupd(
    unsigned short* __restrict__ zhi, unsigned short* __restrict__ zlo,
    unsigned short* __restrict__ zimB,
    const float* __restrict__ xr, const float* __restrict__ xi,
    const float* __restrict__ rc, const float* __restrict__ rs,
    const float* __restrict__ outre, const unsigned short* __restrict__ outim,
    const int* __restrict__ tokcnt, const int* __restrict__ ent_id,
    const float* __restrict__ S) {
    const int n = blockIdx.x;
    const int tid = threadIdx.x;
    const int d0 = tid << 2;
    const int kc = tokcnt[n];
    const int4 e0 = *(const int4*)(ent_id + (n << 3));
    const int4 e1 = *(const int4*)(ent_id + (n << 3) + 4);
    const int rows[8] = {e0.x, e0.y, e0.z, e0.w, e1.x, e1.y, e1.z, e1.w};
    float pr[4] = {0,0,0,0}, pm[4] = {0,0,0,0};
    #pragma unroll
    for (int k = 0; k < 8; ++k) {
        if (k < kc) {
            const int row = rows[k];
            const float s = S[(n << 3) + (row >> 10)];
            const float4 vr = *(const float4*)(outre + ((size_t)row << 10) + d0);
            const ushort4 vi = *(const ushort4*)(outim + ((size_t)row << 10) + d0);
            pr[0] += s * vr.x; pr[1] += s * vr.y; pr[2] += s * vr.z; pr[3] += s * vr.w;
            pm[0] += s * bf2f(vi.x); pm[1] += s * bf2f(vi.y); pm[2] += s * bf2f(vi.z); pm[3] += s * bf2f(vi.w);
        }
    }
    const size_t base = ((size_t)n << 10) + d0;
    const int t = n & (TSEQ - 1);
    float tr[4], ti[4];
    if (t == 0) {
        float4 a = *(const float4*)(xr + base), b = *(const float4*)(xi + base);
        tr[0]=a.x; tr[1]=a.y; tr[2]=a.z; tr[3]=a.w;
        ti[0]=b.x; ti[1]=b.y; ti[2]=b.z; ti[3]=b.w;
    } else {
        float4 a = *(const float4*)(xr + base - DIM), b = *(const float4*)(xi + base - DIM);
        float4 c = *(const float4*)(rc + d0), s4 = *(const float4*)(rs + d0);
        tr[0]=a.x*c.x-b.x*s4.x; tr[1]=a.y*c.y-b.y*s4.y; tr[2]=a.z*c.z-b.z*s4.z; tr[3]=a.w*c.w-b.w*s4.w;
        ti[0]=a.x*s4.x+b.x*c.x; ti[1]=a.y*s4.y+b.y*c.y; ti[2]=a.z*s4.z+b.z*c.z; ti[3]=a.w*s4.w+b.w*c.w;
    }
    ushort4 h4 = *(const ushort4*)(zhi + base);
    ushort4 l4 = *(const ushort4*)(zlo + base);
    ushort4 zi4 = *(const ushort4*)(zimB + base);
    float zrv[4] = {bf2f(h4.x)+bf2f(l4.x), bf2f(h4.y)+bf2f(l4.y),
                    bf2f(h4.z)+bf2f(l4.z), bf2f(h4.w)+bf2f(l4.w)};
    unsigned short ziv[4] = {zi4.x, zi4.y, zi4.z, zi4.w};
    unsigned short hn[4], ln[4], zo[4];
    #pragma unroll
    for (int j = 0; j < 4; ++j) {
        float zn = zrv[j] + 0.5f * (tr[j] - pr[j]);
        unsigned short hb = f2bf(zn);
        hn[j] = hb;
        ln[j] = f2bf(zn - bf2f(hb));
        zo[j] = f2bf(bf2f(ziv[j]) + 0.5f * (ti[j] - pm[j]));
    }
    *(ushort4*)(zhi + base)  = (ushort4){hn[0], hn[1], hn[2], hn[3]};
    *(ushort4*)(zlo + base)  = (ushort4){ln[0], ln[1], ln[2], ln[3]};
    *(ushort4*)(zimB + base) = (ushort4){zo[0], zo[1], zo[2], zo[3]};
}

__global__ void k_write_out(const unsigned short* __restrict__ zhi,
                            const unsigned short* __restrict__ zlo,
                            const unsigned short* __restrict__ zimB,
                            float* __restrict__ out, const int* __restrict__ ctl) {
    int i = blockIdx.x * blockDim.x + threadIdx.x;
    if (i >= ND) return;
    out[2 * i]     = bf2f(zhi[i]) + bf2f(zlo[i]);
    out[2 * i + 1] = bf2f(zimB[i]);
    if (i == 0) out[(size_t)2 * ND] = (float)ctl[1];
}

// ---------------- host ----------------
extern "C" void kernel_launch(void* const* d_in, const int* in_sizes, int n_in,
                              void* d_out, int out_size, void* d_ws, size_t ws_size,
                              hipStream_t stream) {
    (void)in_sizes; (void)n_in; (void)out_size; (void)ws_size;
    const float* x_real = (const float*)d_in[0];
    const float* x_imag = (const float*)d_in[1];
    const float* phase  = (const float*)d_in[2];
    const float* Wg     = (const float*)d_in[3];
    const float* bg     = (const float*)d_in[4];
    const float* We     = (const float*)d_in[5];
    const float* be     = (const float*)d_in[6];
    const int*   Lptr   = (const int*)d_in[7];

    char* wsb = (char*)d_ws;
    unsigned short* zhi  = (unsigned short*)wsb;                      // 16MB
    unsigned short* zlo  = (unsigned short*)(wsb + 16777216);         // 16MB
    unsigned short* zimB = (unsigned short*)(wsb + 33554432);         // 16MB
    unsigned short* Whi  = (unsigned short*)(wsb + 50331648);         // 16MB
    unsigned short* Wlo  = (unsigned short*)(wsb + 67108864);         // 16MB
    float*    S       = (float*)(wsb + 83886080);       // 256KB
    int*      ent_id  = (int*)  (wsb + 84148224);       // 256KB
    int*      idxs    = (int*)  (wsb + 84410368);       // 32KB
    int*      tokcnt  = (int*)  (wsb + 84443136);       // 32KB
    float*    partial = (float*)(wsb + 84475904);       // 128KB
    float*    rc      = (float*)(wsb + 84606976);       // 4KB
    float*    rs      = (float*)(wsb + 84611072);       // 4KB
    int*      ctl     = (int*)  (wsb + 84615168);       // 12B

    float*          outre = (float*)d_out;                       // 32MB fp32 pred.re
    unsigned short* outim = (unsigned short*)((char*)d_out + 33554432);  // 16MB bf16 pred.im

    k_init_small<<<4, 256, 0, stream>>>(phase, Lptr, rc, rs, ctl);
    k_wconv<<<dim3(16, 16, 8), 256, 0, stream>>>(We, Whi, Wlo);
    k_init_gate<<<NTOK / 4, 256, 0, stream>>>(x_real, x_imag, zhi, zlo, zimB, Wg, bg, S, tokcnt);

    const size_t gemm_lds = 40960 * sizeof(unsigned short);   // exactly 80KB
    float lr = 0.5f;
    for (int it = 0; it < 7; ++it) {
        k_route<<<NEXP, 1024, 0, stream>>>(S, idxs, tokcnt, ent_id, ctl, it);
        k_gemm_cx<<<512, 256, gemm_lds, stream>>>(zhi, zlo, zimB, Whi, Wlo, be, idxs,
                                                  outre, outim, ctl, it);
        k_resid_gate<<<NTOK, 256, 0, stream>>>(zhi, zlo, zimB, x_real, x_imag, rc, rs,
                                               outre, outim, tokcnt, ent_id, S, Wg, bg,
                                               lr, partial, ctl, it);
        k_finalize<<<1, 1024, 0, stream>>>(partial, ctl, it);
        lr *= 0.85f;
    }

    k_route<<<NEXP, 1024, 0, stream>>>(S, idxs, tokcnt, ent_id, ctl, -1);
    k_gemm_cx<<<512, 256, gemm_lds, stream>>>(zhi, zlo, zimB, Whi, Wlo, be, idxs,
                                              outre, outim, ctl, -1);
    k_final_zupd<<<NTOK, 256, 0, stream>>>(zhi, zlo, zimB, x_real, x_imag, rc, rs,
                                           outre, outim, tokcnt, ent_id, S);
    k_write_out<<<ND / 256, 256, 0, stream>>>(zhi, zlo, zimB, (float*)d_out, ctl);
}

// Round 20
// 1128.127 us; speedup vs baseline: 3.0512x; 1.0033x over previous
//
#include <hip/hip_runtime.h>
#include <math.h>

#define ND    8388608
#define NTOK  8192
#define DIM   1024
#define NEXP  8
#define CAP   1024
#define TSEQ  2048

typedef short bf16x8 __attribute__((ext_vector_type(8)));
typedef unsigned short u16x8 __attribute__((ext_vector_type(8)));
typedef float f32x4 __attribute__((ext_vector_type(4)));

#define AS1 __attribute__((address_space(1)))
#define AS3 __attribute__((address_space(3)))

__device__ __forceinline__ void gload_lds16(const void* g, void* l) {
    __builtin_amdgcn_global_load_lds((const AS1 unsigned int*)g,
                                     (AS3 unsigned int*)l, 16, 0, 0);
}

__device__ __forceinline__ unsigned short f2bf(float x) {
    union { float f; unsigned u; } v; v.f = x;
    unsigned r = v.u + 0x7FFFu + ((v.u >> 16) & 1u);
    return (unsigned short)(r >> 16);
}
__device__ __forceinline__ float bf2f(unsigned short b) {
    union { unsigned u; float f; } v; v.u = ((unsigned)b) << 16; return v.f;
}

// ---------------- init: rc/rs/ctl ----------------
__global__ void k_init_small(const float* __restrict__ phase, const int* __restrict__ Lptr,
                             float* __restrict__ rc, float* __restrict__ rs,
                             int* __restrict__ ctl) {
    int d = blockIdx.x * blockDim.x + threadIdx.x;
    if (d < DIM) { rc[d] = cosf(phase[d]); rs[d] = sinf(phase[d]); }
    if (d == 0) {
        ctl[0] = 0; ctl[1] = 0;
        int L = Lptr[0]; int mi = L - 1; if (mi < 1) mi = 1;
        ctl[2] = mi;
    }
}

// ---------------- one-time: We -> weT hi/lo bf16, [e][h][d], slot-swizzled by h&7 ----------------
__global__ __launch_bounds__(256) void k_wconv(const float* __restrict__ We,
                                               unsigned short* __restrict__ Whi,
                                               unsigned short* __restrict__ Wlo) {
    __shared__ float lds[64][65];
    int e = blockIdx.z, h0 = blockIdx.x * 64, d0 = blockIdx.y * 64;
    int tid = threadIdx.x;
    #pragma unroll
    for (int q = 0; q < 16; ++q) {
        int idx = q * 256 + tid;
        int i = idx >> 6, j = idx & 63;
        lds[i][j] = We[(size_t)e * 1048576 + (size_t)(d0 + i) * 1024 + h0 + j];
    }
    __syncthreads();
    #pragma unroll
    for (int q = 0; q < 2; ++q) {
        int sid = q * 256 + tid;
        int j = sid >> 3, sp = sid & 7;
        int h = h0 + j;
        int slog = sp ^ (h & 7);
        u16x8 hi, lo;
        #pragma unroll
        for (int u = 0; u < 8; ++u) {
            float x = lds[slog * 8 + u][j];
            unsigned short hb = f2bf(x);
            hi[u] = hb;
            lo[u] = f2bf(x - bf2f(hb));
        }
        size_t o = (((size_t)(e << 10) + h) << 10) + d0 + sp * 8;
        *(u16x8*)(Whi + o) = hi;
        *(u16x8*)(Wlo + o) = lo;
    }
}

// ---------------- fused init + gate ----------------
__global__ __launch_bounds__(256) void k_init_gate(
    const float* __restrict__ xr, const float* __restrict__ xi,
    unsigned short* __restrict__ zhi, unsigned short* __restrict__ zlo,
    unsigned short* __restrict__ zimB,
    const float* __restrict__ Wg, const float* __restrict__ bg,
    float* __restrict__ S, int* __restrict__ tokcnt) {
    const int w = threadIdx.x >> 6, lane = threadIdx.x & 63;
    const int n = blockIdx.x * 4 + w;
    float acc[8] = {0,0,0,0,0,0,0,0};
    #pragma unroll
    for (int q = 0; q < 4; ++q) {
        const int d0 = q * 256 + lane * 4;
        const size_t base = ((size_t)n << 10) + d0;
        float4 xv = *(const float4*)(xr + base);
        float4 iv = *(const float4*)(xi + base);
        float zz[4] = {xv.x, xv.y, xv.z, xv.w};
        float zi[4] = {iv.x, iv.y, iv.z, iv.w};
        unsigned short h4[4], l4[4], i4[4];
        #pragma unroll
        for (int j = 0; j < 4; ++j) {
            unsigned short hb = f2bf(zz[j]);
            h4[j] = hb;
            l4[j] = f2bf(zz[j] - bf2f(hb));
            i4[j] = f2bf(zi[j]);
            const float4 w0 = *(const float4*)(Wg + (d0 + j) * 8);
            const float4 w1 = *(const float4*)(Wg + (d0 + j) * 8 + 4);
            acc[0] += zz[j] * w0.x; acc[1] += zz[j] * w0.y; acc[2] += zz[j] * w0.z; acc[3] += zz[j] * w0.w;
            acc[4] += zz[j] * w1.x; acc[5] += zz[j] * w1.y; acc[6] += zz[j] * w1.z; acc[7] += zz[j] * w1.w;
        }
        *(ushort4*)(zhi + base)  = (ushort4){h4[0], h4[1], h4[2], h4[3]};
        *(ushort4*)(zlo + base)  = (ushort4){l4[0], l4[1], l4[2], l4[3]};
        *(ushort4*)(zimB + base) = (ushort4){i4[0], i4[1], i4[2], i4[3]};
    }
    #pragma unroll
    for (int off = 32; off > 0; off >>= 1)
        #pragma unroll
        for (int e = 0; e < 8; ++e) acc[e] += __shfl_xor(acc[e], off);
    if (lane == 0) {
        float m = -1e30f;
        #pragma unroll
        for (int e = 0; e < 8; ++e) { acc[e] += bg[e]; m = fmaxf(m, acc[e]); }
        float sum = 0.f;
        #pragma unroll
        for (int e = 0; e < 8; ++e) { acc[e] = expf(acc[e] - m); sum += acc[e]; }
        float inv = 1.0f / sum;
        *(float4*)(S + (n << 3))     = (float4){acc[0]*inv, acc[1]*inv, acc[2]*inv, acc[3]*inv};
        *(float4*)(S + (n << 3) + 4) = (float4){acc[4]*inv, acc[5]*inv, acc[6]*inv, acc[7]*inv};
        tokcnt[n] = 0;
    }
}

// ---------------- radix select + emit (fused) ----------------
__global__ __launch_bounds__(1024) void k_route(
    const float* __restrict__ S, int* __restrict__ idxs, int* __restrict__ tokcnt,
    int* __restrict__ ent_id, const int* __restrict__ ctl, int iter) {
    if (iter >= 0 && (ctl[0] || iter >= ctl[2])) return;
    __shared__ unsigned keys[NTOK];
    __shared__ unsigned hA[2048];
    __shared__ unsigned hB[2048];
    __shared__ int sbkt, srem, sntie, scnt;
    const int e = blockIdx.x, tid = threadIdx.x;
    if (tid == 0) scnt = 0;
    for (int n = tid; n < NTOK; n += 1024) keys[n] = __float_as_uint(S[(n << 3) + e]);
    __syncthreads();

    int rem = CAP;
    unsigned pref = 0;
    #pragma unroll
    for (int lvl = 0; lvl < 3; ++lvl) {
        const int nb = (lvl == 2) ? 1024 : 2048;
        for (int i = tid; i < nb; i += 1024) hA[i] = 0;
        __syncthreads();
        for (int n = tid; n < NTOK; n += 1024) {
            unsigned k = keys[n];
            bool ok; unsigned b;
            if (lvl == 0)      { ok = true;                 b = k >> 21; }
            else if (lvl == 1) { ok = (k >> 21) == pref;    b = (k >> 10) & 2047u; }
            else               { ok = (k >> 10) == pref;    b = k & 1023u; }
            if (ok) atomicAdd(&hA[b], 1u);
        }
        __syncthreads();
        unsigned* src = hA; unsigned* dst = hB;
        for (int off = 1; off < nb; off <<= 1) {
            for (int i = tid; i < nb; i += 1024)
                dst[i] = src[i] + ((i + off < nb) ? src[i + off] : 0u);
            __syncthreads();
            unsigned* t = src; src = dst; dst = t;
        }
        for (int i = tid; i < nb; i += 1024) {
            unsigned sfi = src[i];
            unsigned sfn = (i + 1 < nb) ? src[i + 1] : 0u;
            if (sfi >= (unsigned)rem && sfn < (unsigned)rem) {
                sbkt = i; srem = rem - (int)sfn; sntie = (int)(sfi - sfn);
            }
        }
        __syncthreads();
        int b = sbkt; rem = srem;
        if (lvl == 0)      pref = (unsigned)b;
        else if (lvl == 1) pref = (pref << 11) | (unsigned)b;
        else               pref = (pref << 10) | (unsigned)b;
        __syncthreads();
    }
    const unsigned T = pref;
    const int remv = rem;
    const bool allt = (remv == sntie);

    for (int n = tid; n < NTOK; n += 1024) {
        unsigned k = keys[n];
        bool sel = (k > T);
        if (k == T) {
            if (allt) sel = true;
            else {
                int r = 0;
                int j = 0;
                for (; j + 8 <= n; j += 8) {
                    r += (int)(keys[j] == T) + (int)(keys[j+1] == T) + (int)(keys[j+2] == T)
                       + (int)(keys[j+3] == T) + (int)(keys[j+4] == T) + (int)(keys[j+5] == T)
                       + (int)(keys[j+6] == T) + (int)(keys[j+7] == T);
                }
                for (; j < n; ++j) r += (int)(keys[j] == T);
                sel = (r < remv);
            }
        }
        if (sel) {
            int slot = atomicAdd(&scnt, 1);
            int row = (e << 10) + slot;
            idxs[row] = n;
            int p = atomicAdd(&tokcnt[n], 1);
            ent_id[(n << 3) + p] = row;
        }
    }
}

// ---------------- fused complex GEMM: fp32 pred.re, bf16 pred.im ----------------
__global__ __launch_bounds__(256, 2) void k_gemm_cx(
    const unsigned short* __restrict__ zhi, const unsigned short* __restrict__ zlo,
    const unsigned short* __restrict__ zimB,
    const unsigned short* __restrict__ Whi, const unsigned short* __restrict__ Wlo,
    const float* __restrict__ be, const int* __restrict__ idxs,
    float* __restrict__ outre, unsigned short* __restrict__ outim,
    const int* __restrict__ ctl, int iter) {
    if (iter >= 0 && (ctl[0] || iter >= ctl[2])) return;
    extern __shared__ unsigned short smem[];   // 40960 shorts = 80KB
    const int bid = blockIdx.x;
    const int e = bid & 7, bx = (bid >> 3) & 7, by = bid >> 6;
    const int tid = threadIdx.x;
    const int wid = tid >> 6, lane = tid & 63;
    const int wm = wid >> 1, wn = wid & 1;
    const int rl = lane >> 3, ch = lane & 7;
    const int swz8 = (ch ^ rl) << 3;

    int tok[16];
    if (wid < 3) {
        #pragma unroll
        for (int c = 0; c < 16; ++c)
            tok[c] = idxs[(e << 10) + by * 128 + c * 8 + rl];
    }
    const unsigned short* aplane = (wid == 0) ? zhi : (wid == 1) ? zlo : zimB;
    unsigned short* albase = smem + (wid << 13);

    const int wrowbase = (e << 10) + bx * 128;
    const unsigned short* whsrc = Whi + (((size_t)(wrowbase + rl)) << 10) + (ch << 3);
    const unsigned short* wlsrc = Wlo + (((size_t)(wrowbase + rl)) << 10) + (ch << 3);

    f32x4 accre[4][4], accim[4][4];
    #pragma unroll
    for (int a = 0; a < 4; ++a)
        #pragma unroll
        for (int b = 0; b < 4; ++b) {
            accre[a][b] = (f32x4){0.f, 0.f, 0.f, 0.f};
            accim[a][b] = (f32x4){0.f, 0.f, 0.f, 0.f};
        }

    for (int kt = 0; kt < DIM; kt += 64) {
        if (kt) __syncthreads();
        if (wid < 3) {
            #pragma unroll
            for (int c = 0; c < 16; ++c)
                gload_lds16(aplane + (((size_t)tok[c]) << 10) + kt + swz8, albase + c * 512);
        } else {
            #pragma unroll
            for (int c = 0; c < 16; ++c)
                gload_lds16(whsrc + kt + ((size_t)c << 13), smem + 24576 + c * 512);
        }
        #pragma unroll
        for (int q = 0; q < 4; ++q) {
            int c = (wid << 2) + q;
            gload_lds16(wlsrc + kt + ((size_t)c << 13), smem + 32768 + c * 512);
        }
        __syncthreads();
        #pragma unroll
        for (int ks = 0; ks < 2; ++ks) {
            const int slog = (ks << 2) + (lane >> 4);
            const int swz = (slog ^ (lane & 7)) << 3;
            bf16x8 ah[4], al[4], am[4], bh[4], bl[4];
            #pragma unroll
            for (int mi = 0; mi < 4; ++mi) {
                int off = ((wm * 64 + mi * 16 + (lane & 15)) << 6) + swz;
                ah[mi] = *(const bf16x8*)&smem[off];
                al[mi] = *(const bf16x8*)&smem[8192 + off];
                am[mi] = *(const bf16x8*)&smem[16384 + off];
            }
            #pragma unroll
            for (int ni = 0; ni < 4; ++ni) {
                int off = ((wn * 64 + ni * 16 + (lane & 15)) << 6) + swz;
                bh[ni] = *(const bf16x8*)&smem[24576 + off];
                bl[ni] = *(const bf16x8*)&smem[32768 + off];
            }
            #pragma unroll
            for (int mi = 0; mi < 4; ++mi)
                #pragma unroll
                for (int ni = 0; ni < 4; ++ni) {
                    accre[mi][ni] = __builtin_amdgcn_mfma_f32_16x16x32_bf16(ah[mi], bh[ni], accre[mi][ni], 0, 0, 0);
                    accre[mi][ni] = __builtin_amdgcn_mfma_f32_16x16x32_bf16(ah[mi], bl[ni], accre[mi][ni], 0, 0, 0);
                    accre[mi][ni] = __builtin_amdgcn_mfma_f32_16x16x32_bf16(al[mi], bh[ni], accre[mi][ni], 0, 0, 0);
                    accim[mi][ni] = __builtin_amdgcn_mfma_f32_16x16x32_bf16(am[mi], bh[ni], accim[mi][ni], 0, 0, 0);
                }
        }
    }
    const int colbase = bx * 128 + wn * 64 + (lane & 15);
    float bev[4];
    #pragma unroll
    for (int ni = 0; ni < 4; ++ni) bev[ni] = be[(e << 10) + colbase + ni * 16];
    const int rowloc = by * 128 + wm * 64 + ((lane >> 4) << 2);
    float* obr = outre + (((size_t)(e << 10) + rowloc) << 10) + colbase;
    unsigned short* obi = outim + (((size_t)(e << 10) + rowloc) << 10) + colbase;
    #pragma unroll
    for (int mi = 0; mi < 4; ++mi)
        #pragma unroll
        for (int rg = 0; rg < 4; ++rg) {
            size_t ro = (size_t)(mi * 16 + rg) << 10;
            #pragma unroll
            for (int ni = 0; ni < 4; ++ni) {
                obr[ro + ni * 16] = accre[mi][ni][rg] + bev[ni];
                obi[ro + ni * 16] = f2bf(accim[mi][ni][rg]);
            }
        }
}

// ---------------- fused residual + gate (fp32 pred.re, bf16 pred.im) ----------------
__global__ __launch_bounds__(256) void k_resid_gate(
    unsigned short* __restrict__ zhi, unsigned short* __restrict__ zlo,
    unsigned short* __restrict__ zimB,
    const float* __restrict__ xr, const float* __restrict__ xi,
    const float* __restrict__ rc, const float* __restrict__ rs,
    const float* __restrict__ outre, const unsigned short* __restrict__ outim,
    int* __restrict__ tokcnt, const int* __restrict__ ent_id,
    float* __restrict__ S, const float* __restrict__ Wg, const float* __restrict__ bg,
    float lr, float* __restrict__ partial, const int* __restrict__ ctl, int iter) {
    if (ctl[0] || iter >= ctl[2]) return;
    __shared__ float wred[4][8];
    const int n = blockIdx.x;
    const int tid = threadIdx.x;
    const int d0 = tid << 2;
    const int kc = tokcnt[n];
    const int4 e0 = *(const int4*)(ent_id + (n << 3));
    const int4 e1 = *(const int4*)(ent_id + (n << 3) + 4);
    const int rows[8] = {e0.x, e0.y, e0.z, e0.w, e1.x, e1.y, e1.z, e1.w};

    float pr[4] = {0,0,0,0}, pm[4] = {0,0,0,0};
    #pragma unroll
    for (int k = 0; k < 8; ++k) {
        if (k < kc) {
            const int row = rows[k];
            const float s = S[(n << 3) + (row >> 10)];
            const float4 vr = *(const float4*)(outre + ((size_t)row << 10) + d0);
            const ushort4 vi = *(const ushort4*)(outim + ((size_t)row << 10) + d0);
            pr[0] += s * vr.x; pr[1] += s * vr.y; pr[2] += s * vr.z; pr[3] += s * vr.w;
            pm[0] += s * bf2f(vi.x); pm[1] += s * bf2f(vi.y); pm[2] += s * bf2f(vi.z); pm[3] += s * bf2f(vi.w);
        }
    }
    const size_t base = ((size_t)n << 10) + d0;
    const int t = n & (TSEQ - 1);
    float tr[4], ti[4];
    if (t == 0) {
        float4 a = *(const float4*)(xr + base), b = *(const float4*)(xi + base);
        tr[0]=a.x; tr[1]=a.y; tr[2]=a.z; tr[3]=a.w;
        ti[0]=b.x; ti[1]=b.y; ti[2]=b.z; ti[3]=b.w;
    } else {
        float4 a = *(const float4*)(xr + base - DIM), b = *(const float4*)(xi + base - DIM);
        float4 c = *(const float4*)(rc + d0), s4 = *(const float4*)(rs + d0);
        tr[0]=a.x*c.x-b.x*s4.x; tr[1]=a.y*c.y-b.y*s4.y; tr[2]=a.z*c.z-b.z*s4.z; tr[3]=a.w*c.w-b.w*s4.w;
        ti[0]=a.x*s4.x+b.x*c.x; ti[1]=a.y*s4.y+b.y*c.y; ti[2]=a.z*s4.z+b.z*c.z; ti[3]=a.w*s4.w+b.w*c.w;
    }
    ushort4 h4 = *(const ushort4*)(zhi + base);
    ushort4 l4 = *(const ushort4*)(zlo + base);
    ushort4 zi4 = *(const ushort4*)(zimB + base);
    float zrv[4] = {bf2f(h4.x)+bf2f(l4.x), bf2f(h4.y)+bf2f(l4.y),
                    bf2f(h4.z)+bf2f(l4.z), bf2f(h4.w)+bf2f(l4.w)};
    unsigned short ziv[4] = {zi4.x, zi4.y, zi4.z, zi4.w};
    unsigned short hn[4], ln[4], zo[4];
    float lsum = 0.f;
    float lac[8] = {0,0,0,0,0,0,0,0};
    #pragma unroll
    for (int j = 0; j < 4; ++j) {
        float rr = tr[j] - pr[j];
        float ri = ti[j] - pm[j];
        float zn = zrv[j] + lr * rr;
        unsigned short hb = f2bf(zn);
        hn[j] = hb;
        ln[j] = f2bf(zn - bf2f(hb));
        zo[j] = f2bf(bf2f(ziv[j]) + lr * ri);
        lsum += sqrtf(rr * rr + ri * ri);
        const float4 w0 = *(const float4*)(Wg + (d0 + j) * 8);
        const float4 w1 = *(const float4*)(Wg + (d0 + j) * 8 + 4);
        lac[0] += zn * w0.x; lac[1] += zn * w0.y; lac[2] += zn * w0.z; lac[3] += zn * w0.w;
        lac[4] += zn * w1.x; lac[5] += zn * w1.y; lac[6] += zn * w1.z; lac[7] += zn * w1.w;
    }
    *(ushort4*)(zhi + base)  = (ushort4){hn[0], hn[1], hn[2], hn[3]};
    *(ushort4*)(zlo + base)  = (ushort4){ln[0], ln[1], ln[2], ln[3]};
    *(ushort4*)(zimB + base) = (ushort4){zo[0], zo[1], zo[2], zo[3]};

    const int w = tid >> 6, lane = tid & 63;
    #pragma unroll
    for (int off = 32; off > 0; off >>= 1) {
        lsum += __shfl_xor(lsum, off);
        #pragma unroll
        for (int e = 0; e < 8; ++e) lac[e] += __shfl_xor(lac[e], off);
    }
    if (lane == 0) {
        #pragma unroll
        for (int e = 0; e < 8; ++e) wred[w][e] = lac[e];
        partial[(n << 2) + w] = lsum;
    }
    __syncthreads();
    if (tid == 0) {
        float lg[8];
        float m = -1e30f;
        #pragma unroll
        for (int e = 0; e < 8; ++e) {
            lg[e] = wred[0][e] + wred[1][e] + wred[2][e] + wred[3][e] + bg[e];
            m = fmaxf(m, lg[e]);
        }
        float sum = 0.f;
        #pragma unroll
        for (int e = 0; e < 8; ++e) { lg[e] = expf(lg[e] - m); sum += lg[e]; }
        float inv = 1.0f / sum;
        *(float4*)(S + (n << 3))     = (float4){lg[0]*inv, lg[1]*inv, lg[2]*inv, lg[3]*inv};
        *(float4*)(S + (n << 3) + 4) = (float4){lg[4]*inv, lg[5]*inv, lg[6]*inv, lg[7]*inv};
        tokcnt[n] = 0;
    }
}

// ---------------- finalize ----------------
__global__ __launch_bounds__(1024) void k_finalize(
    const float* __restrict__ partial, int* __restrict__ ctl, int iter) {
    if (ctl[0] || iter >= ctl[2]) return;
    __shared__ float red[16];
    float s = 0.f;
    for (int i = threadIdx.x; i < NTOK * 4; i += 1024) s += partial[i];
    #pragma unroll
    for (int off = 32; off > 0; off >>= 1) s += __shfl_xor(s, off);
    if ((threadIdx.x & 63) == 0) red[threadIdx.x >> 6] = s;
    __syncthreads();
    if (threadIdx.x == 0) {
        float tot = 0.f;
        #pragma unroll
        for (int w = 0; w < 16; ++w) tot += red[w];
        ctl[1] = iter + 1;
        if (tot * (1.0f / (float)ND) < 0.001f) ctl[0] = 1;
    }
}

// ---------------- final z update ----------------
__global__ __launch_bounds__(256) void k_final_zupd(
    unsigned short* __restrict__ zhi, unsigned short* __restrict__ zlo,
    unsigned short* __restrict__ zimB,
    const float* __restrict__ xr, const float* __restrict__ xi,
    const float* __restrict__ rc, const float* __restrict__ rs,
    const float* __restrict__ outre, const unsigned short* __restrict__ outim,
    const int* __restrict__ tokcnt, const int* __restrict__ ent_id,
    const float* __restrict__ S) {
    const int n = blockIdx.x;
    const int tid = threadIdx.x;
    const int d0 = tid << 2;
    const int kc = tokcnt[n];
    const int4 e0 = *(const int4*)(ent_id + (n << 3));
    const int4 e1 = *(const int4*)(ent_id + (n << 3) + 4);
    const int rows[8] = {e0.x, e0.y, e0.z, e0.w, e1.x, e1.y, e1.z, e1.w};
    float pr[4] = {0,0,0,0}, pm[4] = {0,0,0,0};
    #pragma unroll
    for (int k = 0; k < 8; ++k) {
        if (k < kc) {
            const int row = rows[k];
            const float s = S[(n << 3) + (row >> 10)];
            const float4 vr = *(const float4*)(outre + ((size_t)row << 10) + d0);
            const ushort4 vi = *(const ushort4*)(outim + ((size_t)row << 10) + d0);
            pr[0] += s * vr.x; pr[1] += s * vr.y; pr[2] += s * vr.z; pr[3] += s * vr.w;
            pm[0] += s * bf2f(vi.x); pm[1] += s * bf2f(vi.y); pm[2] += s * bf2f(vi.z); pm[3] += s * bf2f(vi.w);
        }
    }
    const size_t base = ((size_t)n << 10) + d0;
    const int t = n & (TSEQ - 1);
    float tr[4], ti[4];
    if (t == 0) {
        float4 a = *(const float4*)(xr + base), b = *(const float4*)(xi + base);
        tr[0]=a.x; tr[1]=a.y; tr[2]=a.z; tr[3]=a.w;
        ti[0]=b.x; ti[1]=b.y; ti[2]=b.z; ti[3]=b.w;
    } else {
        float4 a = *(const float4*)(xr + base - DIM), b = *(const float4*)(xi + base - DIM);
        float4 c = *(const float4*)(rc + d0), s4 = *(const float4*)(rs + d0);
        tr[0]=a.x*c.x-b.x*s4.x; tr[1]=a.y*c.y-b.y*s4.y; tr[2]=a.z*c.z-b.z*s4.z; tr[3]=a.w*c.w-b.w*s4.w;
        ti[0]=a.x*s4.x+b.x*c.x; ti[1]=a.y*s4.y+b.y*c.y; ti[2]=a.z*s4.z+b.z*c.z; ti[3]=a.w*s4.w+b.w*c.w;
    }
    ushort4 h4 = *(const ushort4*)(zhi + base);
    ushort4 l4 = *(const ushort4*)(zlo + base);
    ushort4 zi4 = *(const ushort4*)(zimB + base);
    float zrv[4] = {bf2f(h4.x)+bf2f(l4.x), bf2f(h4.y)+bf2f(l4.y),
                    bf2f(h4.z)+bf2f(l4.z), bf2f(h4.w)+bf2f(l4.w)};
    unsigned short ziv[4] = {zi4.x, zi4.y, zi4.z, zi4.w};
    unsigned short hn[4], ln[4], zo[4];
    #pragma unroll
    for (int j = 0; j < 4; ++j) {
        float zn = zrv[j] + 0.5f * (tr[j] - pr[j]);
        unsigned short hb = f2bf(zn);
        hn[j] = hb;
        ln[j] = f2bf(zn - bf2f(hb));
        zo[j] = f2bf(bf2f(ziv[j]) + 0.5f * (ti[j] - pm[j]));
    }
    *(ushort4*)(zhi + base)  = (ushort4){hn[0], hn[1], hn[2], hn[3]};
    *(ushort4*)(zlo + base)  = (ushort4){ln[0], ln[1], ln[2], ln[3]};
    *(ushort4*)(zimB + base) = (ushort4){zo[0], zo[1], zo[2], zo[3]};
}

__global__ void k_write_out(const unsigned short* __restrict__ zhi,
                            const unsigned short* __restrict__ zlo,
                            const unsigned short* __restrict__ zimB,
                            float* __restrict__ out, const int* __restrict__ ctl) {
    int i = blockIdx.x * blockDim.x + threadIdx.x;
    if (i >= ND) return;
    out[2 * i]     = bf2f(zhi[i]) + bf2f(zlo[i]);
    out[2 * i + 1] = bf2f(zimB[i]);
    if (i == 0) out[(size_t)2 * ND] = (float)ctl[1];
}

// ---------------- host ----------------
extern "C" void kernel_launch(void* const* d_in, const int* in_sizes, int n_in,
                              void* d_out, int out_size, void* d_ws, size_t ws_size,
                              hipStream_t stream) {
    (void)in_sizes; (void)n_in; (void)out_size; (void)ws_size;
    const float* x_real = (const float*)d_in[0];
    const float* x_imag = (const float*)d_in[1];
    const float* phase  = (const float*)d_in[2];
    const float* Wg     = (const float*)d_in[3];
    const float* bg     = (const float*)d_in[4];
    const float* We     = (const float*)d_in[5];
    const float* be     = (const float*)d_in[6];
    const int*   Lptr   = (const int*)d_in[7];

    char* wsb = (char*)d_ws;
    unsigned short* zhi  = (unsigned short*)wsb;                      // 16MB
    unsigned short* zlo  = (unsigned short*)(wsb + 16777216);         // 16MB
    unsigned short* zimB = (unsigned short*)(wsb + 33554432);         // 16MB
    unsigned short* Whi  = (unsigned short*)(wsb + 50331648);         // 16MB
    unsigned short* Wlo  = (unsigned short*)(wsb + 67108864);         // 16MB
    float*    S       = (float*)(wsb + 83886080);       // 256KB
    int*      ent_id  = (int*)  (wsb + 84148224);       // 256KB
    int*      idxs    = (int*)  (wsb + 84410368);       // 32KB
    int*      tokcnt  = (int*)  (wsb + 84443136);       // 32KB
    float*    partial = (float*)(wsb + 84475904);       // 128KB
    float*    rc      = (float*)(wsb + 84606976);       // 4KB
    float*    rs      = (float*)(wsb + 84611072);       // 4KB
    int*      ctl     = (int*)  (wsb + 84615168);       // 12B

    float*          outre = (float*)d_out;                       // 32MB fp32 pred.re
    unsigned short* outim = (unsigned short*)((char*)d_out + 33554432);  // 16MB bf16 pred.im

    k_init_small<<<4, 256, 0, stream>>>(phase, Lptr, rc, rs, ctl);
    k_wconv<<<dim3(16, 16, 8), 256, 0, stream>>>(We, Whi, Wlo);
    k_init_gate<<<NTOK / 4, 256, 0, stream>>>(x_real, x_imag, zhi, zlo, zimB, Wg, bg, S, tokcnt);

    const size_t gemm_lds = 40960 * sizeof(unsigned short);   // exactly 80KB
    float lr = 0.5f;
    for (int it = 0; it < 7; ++it) {
        k_route<<<NEXP, 1024, 0, stream>>>(S, idxs, tokcnt, ent_id, ctl, it);
        k_gemm_cx<<<512, 256, gemm_lds, stream>>>(zhi, zlo, zimB, Whi, Wlo, be, idxs,
                                                  outre, outim, ctl, it);
        k_resid_gate<<<NTOK, 256, 0, stream>>>(zhi, zlo, zimB, x_real, x_imag, rc, rs,
                                               outre, outim, tokcnt, ent_id, S, Wg, bg,
                                               lr, partial, ctl, it);
        k_finalize<<<1, 1024, 0, stream>>>(partial, ctl, it);
        lr *= 0.85f;
    }

    k_route<<<NEXP, 1024, 0, stream>>>(S, idxs, tokcnt, ent_id, ctl, -1);
    k_gemm_cx<<<512, 256, gemm_lds, stream>>>(zhi, zlo, zimB, Whi, Wlo, be, idxs,
                                              outre, outim, ctl, -1);
    k_final_zupd<<<NTOK, 256, 0, stream>>>(zhi, zlo, zimB, x_real, x_imag, rc, rs,
                                           outre, outim, tokcnt, ent_id, S);
    k_write_out<<<ND / 256, 256, 0, stream>>>(zhi, zlo, zimB, (float*)d_out, ctl);
}